// Round 8
// baseline (174.630 us; speedup 1.0000x reference)
//
#include <hip/hip_runtime.h>
#include <hip/hip_bf16.h>

typedef __hip_bfloat16 bf16;
typedef _Float16 f16;
typedef __attribute__((ext_vector_type(8))) short bf16x8;
typedef __attribute__((ext_vector_type(8))) _Float16 f16x8;
typedef __attribute__((ext_vector_type(2))) _Float16 f16x2;
typedef __attribute__((ext_vector_type(4))) float f32x4;
typedef __attribute__((ext_vector_type(4))) unsigned int u32x4;
typedef __attribute__((ext_vector_type(2))) unsigned int u32x2;

#define B_ 4
#define N_ 4096
#define C_ 256
#define H_ 4
#define D_ 64
#define KLN 0.18033688011112042f   /* 0.125 * log2(e): folded into Q */

#if __has_builtin(__builtin_amdgcn_exp2f)
#define EXP2(x) __builtin_amdgcn_exp2f(x)
#else
#define EXP2(x) exp2f(x)
#endif
#if __has_builtin(__builtin_amdgcn_rcpf)
#define RCP(x) __builtin_amdgcn_rcpf(x)
#else
#define RCP(x) (1.0f / (x))
#endif

// direct global->LDS DMA, 16B per lane. LDS dest = wave-uniform base + lane*16.
__device__ inline void load_lds16(const void* g, void* l) {
#if __has_builtin(__builtin_amdgcn_global_load_lds)
    __builtin_amdgcn_global_load_lds(
        (const __attribute__((address_space(1))) unsigned int*)g,
        (__attribute__((address_space(3))) unsigned int*)l, 16, 0, 0);
#else
    int ln = __lane_id();
    ((u32x4*)l)[ln] = *((const u32x4*)g);   // fallback (not used on gfx950)
#endif
}

// two fp32 -> packed bf16 pair (round-half-up)
__device__ inline unsigned int pk2(float a, float b) {
    unsigned int ua = __builtin_bit_cast(unsigned int, a) + 0x8000u;
    unsigned int ub = __builtin_bit_cast(unsigned int, b) + 0x8000u;
    return (ua >> 16) | (ub & 0xffff0000u);
}
// two fp32 -> packed f16 pair (single v_cvt_pkrtz_f16_f32)
__device__ inline unsigned int pkh2(float a, float b) {
#if __has_builtin(__builtin_amdgcn_cvt_pkrtz)
    return __builtin_bit_cast(unsigned int, __builtin_amdgcn_cvt_pkrtz(a, b));
#else
    f16x2 h = { (f16)a, (f16)b };
    return __builtin_bit_cast(unsigned int, h);
#endif
}

// ---------------------------------------------------------------------------
// Prep: cast x, w_qkv, w_proj fp32 -> bf16 (memory-bound).
// ---------------------------------------------------------------------------
__global__ __launch_bounds__(256) void cast_bf16(const float* __restrict__ x,
                                                 const float* __restrict__ wq,
                                                 const float* __restrict__ wp,
                                                 bf16* __restrict__ xb,
                                                 bf16* __restrict__ wqb,
                                                 bf16* __restrict__ wpb)
{
    int bid = blockIdx.x;
    const float* s; bf16* d; int base;
    if (bid < 2048)      { s = x;  d = xb;  base = bid * 2048; }
    else if (bid < 2144) { s = wq; d = wqb; base = (bid - 2048) * 2048; }
    else                 { s = wp; d = wpb; base = (bid - 2144) * 2048; }
    int i = base + threadIdx.x * 8;
    f32x4 a = *reinterpret_cast<const f32x4*>(s + i);
    f32x4 b = *reinterpret_cast<const f32x4*>(s + i + 4);
    u32x4 o;
    o.x = pk2(a[0], a[1]); o.y = pk2(a[2], a[3]);
    o.z = pk2(b[0], b[1]); o.w = pk2(b[2], b[3]);
    *reinterpret_cast<u32x4*>(d + i) = o;
}

// ---------------------------------------------------------------------------
// QKV projection — round-3 version (best measured non-attn config).
// ---------------------------------------------------------------------------
__global__ __launch_bounds__(256, 2) void qkv_fast(const bf16* __restrict__ x,
                                                   const bf16* __restrict__ w,
                                                   bf16* __restrict__ qw,
                                                   bf16* __restrict__ kw,
                                                   f16* __restrict__ vtw)
{
    __shared__ short w_s[64][264];
    const int tid  = threadIdx.x;
    const int lane = tid & 63;
    const int wav  = tid >> 6;
    const int quad = lane >> 4;
    const int l16  = lane & 15;
    const int bid = (blockIdx.x & 7) * 192 + (blockIdx.x >> 3);   // 1536 = 8*192
    const int mt = bid / 12, nb = bid % 12;
    const int m0 = mt * 128, n0 = nb * 64;

    {
        const int row = tid >> 2, cb = (tid & 3) * 64;
        const bf16* src = w + (size_t)(n0 + row) * C_ + cb;
#pragma unroll
        for (int i = 0; i < 8; ++i)
            *reinterpret_cast<bf16x8*>(&w_s[row][cb + i * 8]) =
                *reinterpret_cast<const bf16x8*>(src + i * 8);
    }
    __syncthreads();

#pragma unroll
    for (int half = 0; half < 2; ++half) {
        const int mh = m0 + half * 64;
        f32x4 acc[4] = {{0,0,0,0},{0,0,0,0},{0,0,0,0},{0,0,0,0}};
        const bf16* xrow = x + (size_t)(mh + wav * 16 + l16) * C_ + quad * 8;
        if (nb < 8) {        // Q/K: transposed accumulator (swapped operands)
#pragma unroll
            for (int k0 = 0; k0 < C_; k0 += 32) {
                bf16x8 a = *reinterpret_cast<const bf16x8*>(xrow + k0);
#pragma unroll
                for (int nt = 0; nt < 4; ++nt) {
                    bf16x8 b = *reinterpret_cast<const bf16x8*>(&w_s[nt * 16 + l16][k0 + quad * 8]);
                    acc[nt] = __builtin_amdgcn_mfma_f32_16x16x32_bf16(b, a, acc[nt], 0, 0, 0);
                }
            }
        } else {             // V: normal orientation (store wants n-contiguous)
#pragma unroll
            for (int k0 = 0; k0 < C_; k0 += 32) {
                bf16x8 a = *reinterpret_cast<const bf16x8*>(xrow + k0);
#pragma unroll
                for (int nt = 0; nt < 4; ++nt) {
                    bf16x8 b = *reinterpret_cast<const bf16x8*>(&w_s[nt * 16 + l16][k0 + quad * 8]);
                    acc[nt] = __builtin_amdgcn_mfma_f32_16x16x32_bf16(a, b, acc[nt], 0, 0, 0);
                }
            }
        }

        const int bb = mh >> 12;
        const int nbase = (mh + wav * 16) & (N_ - 1);
        if (nb < 4) {                            // Q (scaled): row n = nbase+l16
            bf16* dst = qw + (((size_t)bb * H_ + nb) * N_ + nbase + l16) * D_;
#pragma unroll
            for (int nt = 0; nt < 4; ++nt) {
                u32x2 wv = { pk2(acc[nt][0] * KLN, acc[nt][1] * KLN),
                             pk2(acc[nt][2] * KLN, acc[nt][3] * KLN) };
                *reinterpret_cast<u32x2*>(dst + nt * 16 + quad * 4) = wv;
            }
        } else if (nb < 8) {                     // K
            bf16* dst = kw + (((size_t)bb * H_ + (nb - 4)) * N_ + nbase + l16) * D_;
#pragma unroll
            for (int nt = 0; nt < 4; ++nt) {
                u32x2 wv = { pk2(acc[nt][0], acc[nt][1]),
                             pk2(acc[nt][2], acc[nt][3]) };
                *reinterpret_cast<u32x2*>(dst + nt * 16 + quad * 4) = wv;
            }
        } else {                                 // V transposed, f16
            const int h = nb - 8;
#pragma unroll
            for (int nt = 0; nt < 4; ++nt) {
                int d = nt * 16 + l16;
                u32x2 wv;
                wv.x = pkh2(acc[nt][0], acc[nt][1]);
                wv.y = pkh2(acc[nt][2], acc[nt][3]);
                *reinterpret_cast<u32x2*>(
                    vtw + (((size_t)bb * H_ + h) * D_ + d) * N_ + nbase + quad * 4) = wv;
            }
        }
    }
}

// ---------------------------------------------------------------------------
// Flash attention v11 = r1 structure (best measured) + register hoisting.
// r7's counters: VGPR_Count=64 (half the 128 budget) with VALUBusy 47% —
// the compiler rematerializes LDS fragment addresses and staging pointers
// every tile instead of holding them. v11 unrolls the tile loop x2 (explicit
// buf0/buf1 bodies) and hoists ALL loop-invariant addresses into named
// registers: 8 fragment base pointers (2 buf x {K,V} x 2 k-slots; fragments
// are base + nt*1024 const offsets -> ds_read immediates), 4 strength-
// reduced staging sources (+= 64*D / += 64 per tile), 8 uniform staging
// dests. Single V read shared by both q-groups (r1 style). Everything else
// identical to r1/r7: 512-thr 8-wave blocks, 2 q-groups, K+V LDS dbuf,
// pi K-row permutation, in-register P, ones-MFMA l, 1 barrier/tile.
// Bit-identical arithmetic.
// ---------------------------------------------------------------------------
__global__ __launch_bounds__(512, 4) void attn(const bf16* __restrict__ q,
                                               const bf16* __restrict__ k,
                                               const f16* __restrict__ vt,
                                               bf16* __restrict__ o)
{
    __shared__ __align__(16) char smem[65536];
    short* k_s = reinterpret_cast<short*>(smem);            // [buf][jh][64*64]
    f16*   v_s = reinterpret_cast<f16*>(smem + 32768);      // [buf][jh][64*64]

    const int tid  = threadIdx.x;
    const int lane = tid & 63;
    const int wav  = tid >> 6;       // 0..7
    const int quad = lane >> 4;
    const int l16  = lane & 15;
    const int l8   = lane & 7;
    const int sub  = wav & 3;        // 32-row q-slice within the 128-row tile
    const int jh   = wav >> 2;       // j-half

    const int wg = (blockIdx.x & 7) * 64 + (blockIdx.x >> 3);  // XCD swizzle
    const int bh = wg >> 5;
    const int qt = wg & 31;
    const int bb = bh >> 2, h = bh & 3;

    const bf16* qp = q  + (size_t)bh * N_ * D_;
    const bf16* kp = k  + (size_t)bh * N_ * D_;
    const f16*  vp = vt + (size_t)bh * D_ * N_;

    const int qbase = qt * 128 + sub * 32;
    bf16x8 qb[2][2];
#pragma unroll
    for (int qg = 0; qg < 2; ++qg)
#pragma unroll
        for (int ks = 0; ks < 2; ++ks)
            qb[qg][ks] = *reinterpret_cast<const bf16x8*>(
                qp + (size_t)(qbase + qg * 16 + l16) * D_ + ks * 32 + quad * 8);

    // staging geometry: lane -> (row ri, stored slot ci); logical chunk = ci^ri
    const int ri = lane >> 3;
    const int ci = lane & 7;
    const int gc = ci ^ ri;
    const int rb0 = sub * 16;            // this wave's 16-row staging groups
    const int rb1 = sub * 16 + 8;
    const int rho0 = rb0 + ri, rho1 = rb1 + ri;
    const int pr0 = (rho0 & 32) | ((rho0 & 12) << 1) | ((rho0 & 16) >> 2) | (rho0 & 3);
    const int pr1 = (rho1 & 32) | ((rho1 & 12) << 1) | ((rho1 & 16) >> 2) | (rho1 & 3);

    const int j00 = jh * 2048;

    // strength-reduced staging SOURCE pointers (start at tile 1; tile 0 in
    // the prologue reads them at -1 step)
    const bf16* ksrc0 = kp + (size_t)(j00 + 64) * D_ + pr0 * D_ + gc * 8;
    const bf16* ksrc1 = kp + (size_t)(j00 + 64) * D_ + pr1 * D_ + gc * 8;
    const f16*  vsrc0 = vp + (size_t)rho0 * N_ + j00 + 64 + gc * 8;
    const f16*  vsrc1 = vp + (size_t)rho1 * N_ + j00 + 64 + gc * 8;

    // wave-uniform staging DEST pointers, both buffers
    short* kdst0g0 = k_s + (0 * 2 + jh) * 4096 + rb0 * 64;
    short* kdst0g1 = k_s + (0 * 2 + jh) * 4096 + rb1 * 64;
    short* kdst1g0 = k_s + (1 * 2 + jh) * 4096 + rb0 * 64;
    short* kdst1g1 = k_s + (1 * 2 + jh) * 4096 + rb1 * 64;
    f16* vdst0g0 = v_s + (0 * 2 + jh) * 4096 + rb0 * 64;
    f16* vdst0g1 = v_s + (0 * 2 + jh) * 4096 + rb1 * 64;
    f16* vdst1g0 = v_s + (1 * 2 + jh) * 4096 + rb0 * 64;
    f16* vdst1g1 = v_s + (1 * 2 + jh) * 4096 + rb1 * 64;

    // hoisted fragment BASE pointers (per buffer, per k-slot); fragment
    // (nt or dt) = base + nt*1024 -> folds into ds_read offset immediates
    const int fragA = l16 * 64 + ((quad    ) ^ l8) * 8;
    const int fragB = l16 * 64 + ((4 + quad) ^ l8) * 8;
    const short* kb0A = k_s + (0 * 2 + jh) * 4096 + fragA;
    const short* kb0B = k_s + (0 * 2 + jh) * 4096 + fragB;
    const short* kb1A = k_s + (1 * 2 + jh) * 4096 + fragA;
    const short* kb1B = k_s + (1 * 2 + jh) * 4096 + fragB;
    const f16* vb0A = v_s + (0 * 2 + jh) * 4096 + fragA;
    const f16* vb0B = v_s + (0 * 2 + jh) * 4096 + fragB;
    const f16* vb1A = v_s + (1 * 2 + jh) * 4096 + fragA;
    const f16* vb1B = v_s + (1 * 2 + jh) * 4096 + fragB;

    f32x4 oacc[2][4];
    f32x4 lacc[2];
#pragma unroll
    for (int qg = 0; qg < 2; ++qg) {
        lacc[qg] = (f32x4){0, 0, 0, 0};
#pragma unroll
        for (int dt = 0; dt < 4; ++dt) oacc[qg][dt] = (f32x4){0, 0, 0, 0};
    }
    const f16x8 onesA = {1.f16, 1.f16, 1.f16, 1.f16, 1.f16, 1.f16, 1.f16, 1.f16};

    // prologue: stage tile 0 into buf0 (sources at tile 0 = src - 1 step)
    load_lds16(ksrc0 - 64 * D_, kdst0g0);
    load_lds16(ksrc1 - 64 * D_, kdst0g1);
    load_lds16(vsrc0 - 64,      vdst0g0);
    load_lds16(vsrc1 - 64,      vdst0g1);
    __syncthreads();

    auto tile_body = [&](const short* kbA, const short* kbB,
                         const f16* vbA, const f16* vbB,
                         short* kdg0, short* kdg1, f16* vdg0, f16* vdg1,
                         bool do_stage) {
        if (do_stage) {
            load_lds16(ksrc0, kdg0);
            load_lds16(ksrc1, kdg1);
            load_lds16(vsrc0, vdg0);
            load_lds16(vsrc1, vdg1);
            ksrc0 += 64 * D_; ksrc1 += 64 * D_;
            vsrc0 += 64;      vsrc1 += 64;
        }

        // K fragments (shared across both q-groups)
        bf16x8 ka[4][2];
#pragma unroll
        for (int nt = 0; nt < 4; ++nt) {
            ka[nt][0] = *reinterpret_cast<const bf16x8*>(kbA + nt * 1024);
            ka[nt][1] = *reinterpret_cast<const bf16x8*>(kbB + nt * 1024);
        }

        // S^T = K.Q^T per q-group; p = exp2(s); l via ones-MFMA
        f16x8 pb[2][2];
#pragma unroll
        for (int qg = 0; qg < 2; ++qg) {
            f32x4 s[4];
#pragma unroll
            for (int nt = 0; nt < 4; ++nt) {
                s[nt] = __builtin_amdgcn_mfma_f32_16x16x32_bf16(
                    ka[nt][0], qb[qg][0], (f32x4){0.f, 0.f, 0.f, 0.f}, 0, 0, 0);
                s[nt] = __builtin_amdgcn_mfma_f32_16x16x32_bf16(
                    ka[nt][1], qb[qg][1], s[nt], 0, 0, 0);
            }
#pragma unroll
            for (int ks = 0; ks < 2; ++ks) {
                const f32x4 sa = s[2 * ks], sb = s[2 * ks + 1];
                u32x4 pw;
                pw.x = pkh2(EXP2(sa[0]), EXP2(sa[1]));
                pw.y = pkh2(EXP2(sa[2]), EXP2(sa[3]));
                pw.z = pkh2(EXP2(sb[0]), EXP2(sb[1]));
                pw.w = pkh2(EXP2(sb[2]), EXP2(sb[3]));
                pb[qg][ks] = __builtin_bit_cast(f16x8, pw);
                lacc[qg] = __builtin_amdgcn_mfma_f32_16x16x32_f16(onesA, pb[qg][ks], lacc[qg], 0, 0, 0);
            }
        }

        // O^T += V^T . P^T (each V fragment read once, used by both q-groups)
#pragma unroll
        for (int dt = 0; dt < 4; ++dt) {
            f16x8 va0 = *reinterpret_cast<const f16x8*>(vbA + dt * 1024);
            oacc[0][dt] = __builtin_amdgcn_mfma_f32_16x16x32_f16(va0, pb[0][0], oacc[0][dt], 0, 0, 0);
            oacc[1][dt] = __builtin_amdgcn_mfma_f32_16x16x32_f16(va0, pb[1][0], oacc[1][dt], 0, 0, 0);
            f16x8 va1 = *reinterpret_cast<const f16x8*>(vbB + dt * 1024);
            oacc[0][dt] = __builtin_amdgcn_mfma_f32_16x16x32_f16(va1, pb[0][1], oacc[0][dt], 0, 0, 0);
            oacc[1][dt] = __builtin_amdgcn_mfma_f32_16x16x32_f16(va1, pb[1][1], oacc[1][dt], 0, 0, 0);
        }

        __syncthreads();   // drains this wave's DMA (next tile) + fences reads
    };

    for (int tt = 0; tt < 16; ++tt) {
        // t = 2tt: compute buf0, stage t+1 into buf1 (always: 2tt+1 <= 31)
        tile_body(kb0A, kb0B, vb0A, vb0B, kdst1g0, kdst1g1, vdst1g0, vdst1g1, true);
        // t = 2tt+1: compute buf1, stage t+2 into buf0 (except last)
        tile_body(kb1A, kb1B, vb1A, vb1B, kdst0g0, kdst0g1, vdst0g0, vdst0g1, tt < 15);
    }

    // ---- merge j-halves (exact: O and l add) via lane-to-lane LDS slots ----
    __syncthreads();                  // staging reads done; reuse as merge buf
    float* mrg = reinterpret_cast<float*>(smem);
    const int slot = (sub * 64 + lane) * 35;       // odd stride: no conflicts
    if (jh == 1) {
#pragma unroll
        for (int qg = 0; qg < 2; ++qg) {
#pragma unroll
            for (int dt = 0; dt < 4; ++dt)
#pragma unroll
                for (int e = 0; e < 4; ++e)
                    mrg[slot + qg * 17 + dt * 4 + e] = oacc[qg][dt][e];
            mrg[slot + qg * 17 + 16] = lacc[qg][0];
        }
    }
    __syncthreads();
    if (jh == 0) {
#pragma unroll
        for (int qg = 0; qg < 2; ++qg) {
            const float rl = RCP(lacc[qg][0] + mrg[slot + qg * 17 + 16]);
            const size_t obase = ((size_t)bb * N_ + qbase + qg * 16 + l16) * C_ + h * D_;
#pragma unroll
            for (int dt = 0; dt < 4; ++dt) {
                float v0 = (oacc[qg][dt][0] + mrg[slot + qg * 17 + dt * 4 + 0]) * rl;
                float v1 = (oacc[qg][dt][1] + mrg[slot + qg * 17 + dt * 4 + 1]) * rl;
                float v2 = (oacc[qg][dt][2] + mrg[slot + qg * 17 + dt * 4 + 2]) * rl;
                float v3 = (oacc[qg][dt][3] + mrg[slot + qg * 17 + dt * 4 + 3]) * rl;
                u32x2 wv = { pk2(v0, v1), pk2(v2, v3) };
                *reinterpret_cast<u32x2*>(o + obase + dt * 16 + quad * 4) = wv;
            }
        }
    }
}

// ---------------------------------------------------------------------------
// Output projection — round-3 version.
// ---------------------------------------------------------------------------
__global__ __launch_bounds__(256, 2) void out_proj_fast(const bf16* __restrict__ ov,
                                                        const bf16* __restrict__ w,
                                                        const float* __restrict__ bias,
                                                        float* __restrict__ out)
{
    __shared__ short w_s[64][264];
    const int tid  = threadIdx.x;
    const int lane = tid & 63;
    const int wav  = tid >> 6;
    const int quad = lane >> 4;
    const int l16  = lane & 15;
    const int bid = (blockIdx.x & 7) * 64 + (blockIdx.x >> 3);   // 512 = 8*64
    const int m0 = (bid >> 2) * 128;
    const int n0 = (bid & 3) * 64;

    {
        const int row = tid >> 2, cb = (tid & 3) * 64;
        const bf16* src = w + (size_t)(n0 + row) * C_ + cb;
#pragma unroll
        for (int i = 0; i < 8; ++i)
            *reinterpret_cast<bf16x8*>(&w_s[row][cb + i * 8]) =
                *reinterpret_cast<const bf16x8*>(src + i * 8);
    }
    __syncthreads();

#pragma unroll
    for (int half = 0; half < 2; ++half) {
        const int mh = m0 + half * 64;
        f32x4 acc[4] = {{0,0,0,0},{0,0,0,0},{0,0,0,0},{0,0,0,0}};
        const bf16* orow = ov + (size_t)(mh + wav * 16 + l16) * C_ + quad * 8;
#pragma unroll
        for (int k0 = 0; k0 < C_; k0 += 32) {
            bf16x8 a = *reinterpret_cast<const bf16x8*>(orow + k0);
#pragma unroll
            for (int nt = 0; nt < 4; ++nt) {
                bf16x8 b = *reinterpret_cast<const bf16x8*>(&w_s[nt * 16 + l16][k0 + quad * 8]);
                acc[nt] = __builtin_amdgcn_mfma_f32_16x16x32_bf16(b, a, acc[nt], 0, 0, 0);
            }
        }
        const int m = mh + wav * 16 + l16;
#pragma unroll
        for (int nt = 0; nt < 4; ++nt) {
            const int oc0 = n0 + nt * 16 + quad * 4;
            f32x4 bv = *reinterpret_cast<const f32x4*>(bias + oc0);
            f32x4 ovv = acc[nt] + bv;
            *reinterpret_cast<f32x4*>(out + (size_t)m * C_ + oc0) = ovv;
        }
    }
}

extern "C" void kernel_launch(void* const* d_in, const int* in_sizes, int n_in,
                              void* d_out, int out_size, void* d_ws, size_t ws_size,
                              hipStream_t stream) {
    const float* x      = (const float*)d_in[0];
    const float* w_qkv  = (const float*)d_in[1];
    const float* w_proj = (const float*)d_in[2];
    const float* b_proj = (const float*)d_in[3];
    float* out = (float*)d_out;

    const size_t qkv_elems = (size_t)B_ * H_ * N_ * D_;   // 4,194,304
    bf16* q_ws  = (bf16*)d_ws;
    bf16* k_ws  = q_ws  + qkv_elems;
    f16*  vt_ws = (f16*)(k_ws + qkv_elems);
    bf16* o_ws  = (bf16*)(vt_ws + qkv_elems);
    bf16* x_bf  = o_ws  + qkv_elems;
    bf16* wq_bf = x_bf  + (size_t)B_ * N_ * C_;
    bf16* wp_bf = wq_bf + (size_t)3 * C_ * C_;

    cast_bf16    <<<2176, 256, 0, stream>>>(x, w_qkv, w_proj, x_bf, wq_bf, wp_bf);
    qkv_fast     <<<1536, 256, 0, stream>>>(x_bf, wq_bf, q_ws, k_ws, vt_ws);
    attn         <<< 512, 512, 0, stream>>>(q_ws, k_ws, vt_ws, o_ws);
    out_proj_fast<<< 512, 256, 0, stream>>>(o_ws, wp_bf, b_proj, out);
}